// Round 6
// baseline (636.509 us; speedup 1.0000x reference)
//
#include <hip/hip_runtime.h>
#include <hip/hip_cooperative_groups.h>

namespace cg = cooperative_groups;

typedef float vf4 __attribute__((ext_vector_type(4)));

#define NB 1024      // 4 blocks/CU on 256 CUs -> all co-resident for cooperative launch
#define NT 256       // threads/block (4 waves)

__device__ __forceinline__ void nt_store4(float4* p, float4 v) {
    __builtin_nontemporal_store(*reinterpret_cast<vf4*>(&v), reinterpret_cast<vf4*>(p));
}
__device__ __forceinline__ float4 nt_load4(const float4* p) {
    vf4 t = __builtin_nontemporal_load(reinterpret_cast<const vf4*>(p));
    float4 r; r.x = t.x; r.y = t.y; r.z = t.z; r.w = t.w;
    return r;
}

// block-level min/max reduce; result valid in thread 0 only
__device__ __forceinline__ void block_minmax(float& mn, float& mx,
                                             volatile float* smn, volatile float* smx) {
    #pragma unroll
    for (int off = 32; off > 0; off >>= 1) {
        mn = fminf(mn, __shfl_down(mn, off, 64));
        mx = fmaxf(mx, __shfl_down(mx, off, 64));
    }
    int wave = threadIdx.x >> 6;
    int lane = threadIdx.x & 63;
    if (lane == 0) { smn[wave] = mn; smx[wave] = mx; }
    __syncthreads();
    if (threadIdx.x == 0) {
        #pragma unroll
        for (int w = 1; w < NT / 64; ++w) {
            mn = fminf(mn, smn[w]);
            mx = fmaxf(mx, smx[w]);
        }
    }
}

__device__ __forceinline__ float spline_eval(float xv, float mn, float scale,
                                             const float* sk, const float* sa,
                                             const float* sb, float klo, float khi) {
    float xn = (xv - mn) * scale;
    // initial bin estimate (knots ~ uniform on [0,1]) + boundary correction
    // -> searchsorted(right)-1 semantics
    int b = (int)(xn * 31.0f);
    b = b < 0 ? 0 : (b > 30 ? 30 : b);
    if (xn < sk[b]) {
        b = (b > 0) ? b - 1 : 0;
    } else if (xn >= sk[b + 1]) {
        b = (b < 30) ? b + 1 : 30;
    }
    float val = fmaf(xn - sk[b], sb[b], sa[b]);
    return (xn >= klo && xn <= khi) ? val : 0.0f;
}

__global__ __launch_bounds__(NT, 4) void spline_fused(const float4* __restrict__ x,
                                                      const float* __restrict__ cp,
                                                      const float* __restrict__ knots,
                                                      float* __restrict__ ws,
                                                      float4* __restrict__ out, int n4) {
    __shared__ float sk[32];        // knots
    __shared__ float sa[32];        // control points
    __shared__ float sb[32];        // per-bin slope
    __shared__ float smn[NT / 64], smx[NT / 64];
    __shared__ float sbc[2];        // broadcast of final min/max

    if (threadIdx.x < 32) {
        sk[threadIdx.x] = knots[threadIdx.x];
        sa[threadIdx.x] = cp[threadIdx.x];
    }
    __syncthreads();
    if (threadIdx.x < 31) {
        int i = threadIdx.x;
        sb[i] = (sa[i + 1] - sa[i]) / (sk[i + 1] - sk[i]);
    }
    // sb consumed only after grid sync below (which includes a block-level sync)

    const int gtid   = blockIdx.x * NT + threadIdx.x;
    const int stride = NB * NT;

    // ---------- phase 1: grid-stride min/max, ASCENDING temporal loads ----------
    // (streams x through L2/L3, leaving the tail of x hottest in the 256 MiB L3)
    float mn = INFINITY, mx = -INFINITY;
    int i = gtid;
    for (; i + stride < n4; i += 2 * stride) {       // 2 independent loads in flight
        float4 a = x[i];
        float4 b = x[i + stride];
        mn = fminf(mn, fminf(fminf(a.x, a.y), fminf(a.z, a.w)));
        mx = fmaxf(mx, fmaxf(fmaxf(a.x, a.y), fmaxf(a.z, a.w)));
        mn = fminf(mn, fminf(fminf(b.x, b.y), fminf(b.z, b.w)));
        mx = fmaxf(mx, fmaxf(fmaxf(b.x, b.y), fmaxf(b.z, b.w)));
    }
    for (; i < n4; i += stride) {
        float4 a = x[i];
        mn = fminf(mn, fminf(fminf(a.x, a.y), fminf(a.z, a.w)));
        mx = fmaxf(mx, fmaxf(fmaxf(a.x, a.y), fmaxf(a.z, a.w)));
    }
    block_minmax(mn, mx, smn, smx);
    if (threadIdx.x == 0) {
        // agent-scope stores: visible across XCD L2s after the grid barrier
        __hip_atomic_store(&ws[blockIdx.x],      mn, __ATOMIC_RELAXED, __HIP_MEMORY_SCOPE_AGENT);
        __hip_atomic_store(&ws[NB + blockIdx.x], mx, __ATOMIC_RELAXED, __HIP_MEMORY_SCOPE_AGENT);
        __threadfence();
    }

    cg::this_grid().sync();

    // ---------- phase 2: every block redundantly reduces the NB partials ----------
    mn = INFINITY; mx = -INFINITY;
    for (int j = threadIdx.x; j < NB; j += NT) {
        mn = fminf(mn, __hip_atomic_load(&ws[j],      __ATOMIC_RELAXED, __HIP_MEMORY_SCOPE_AGENT));
        mx = fmaxf(mx, __hip_atomic_load(&ws[NB + j], __ATOMIC_RELAXED, __HIP_MEMORY_SCOPE_AGENT));
    }
    block_minmax(mn, mx, smn, smx);
    if (threadIdx.x == 0) { sbc[0] = mn; sbc[1] = mx; }
    __syncthreads();
    mn = sbc[0]; mx = sbc[1];

    const float scale = 1.0f / (mx - mn + 1e-6f);
    const float klo = sk[0], khi = sk[31];

    // ---------- phase 3: apply, BACKWARD traversal (anti-LRU: tail of x is
    // hottest in L3), nontemporal x-loads (single-use) and out-stores (must not
    // evict x from the memory-side Infinity Cache) ----------
    const int KMAX = (n4 + stride - 1) / stride;
    int k = KMAX - 1;
    for (; k >= 1; k -= 2) {
        const int i0 = k * stride + gtid;           // only possibly OOB at k = KMAX-1
        const int i1 = (k - 1) * stride + gtid;     // always in bounds
        const bool ok0 = (i0 < n4);
        float4 v0 = ok0 ? nt_load4(&x[i0]) : make_float4(0.f, 0.f, 0.f, 0.f);
        float4 v1 = nt_load4(&x[i1]);
        float4 r0, r1;
        r0.x = spline_eval(v0.x, mn, scale, sk, sa, sb, klo, khi);
        r0.y = spline_eval(v0.y, mn, scale, sk, sa, sb, klo, khi);
        r0.z = spline_eval(v0.z, mn, scale, sk, sa, sb, klo, khi);
        r0.w = spline_eval(v0.w, mn, scale, sk, sa, sb, klo, khi);
        r1.x = spline_eval(v1.x, mn, scale, sk, sa, sb, klo, khi);
        r1.y = spline_eval(v1.y, mn, scale, sk, sa, sb, klo, khi);
        r1.z = spline_eval(v1.z, mn, scale, sk, sa, sb, klo, khi);
        r1.w = spline_eval(v1.w, mn, scale, sk, sa, sb, klo, khi);
        if (ok0) nt_store4(&out[i0], r0);
        nt_store4(&out[i1], r1);
    }
    if (k == 0) {
        const int i0 = gtid;
        if (i0 < n4) {
            float4 v0 = nt_load4(&x[i0]);
            float4 r0;
            r0.x = spline_eval(v0.x, mn, scale, sk, sa, sb, klo, khi);
            r0.y = spline_eval(v0.y, mn, scale, sk, sa, sb, klo, khi);
            r0.z = spline_eval(v0.z, mn, scale, sk, sa, sb, klo, khi);
            r0.w = spline_eval(v0.w, mn, scale, sk, sa, sb, klo, khi);
            nt_store4(&out[i0], r0);
        }
    }
}

extern "C" void kernel_launch(void* const* d_in, const int* in_sizes, int n_in,
                              void* d_out, int out_size, void* d_ws, size_t ws_size,
                              hipStream_t stream) {
    const float4* x     = (const float4*)d_in[0];
    const float*  cp    = (const float*)d_in[1];
    const float*  knots = (const float*)d_in[2];
    float*  ws  = (float*)d_ws;
    float4* out = (float4*)d_out;

    int n  = in_sizes[0];      // 64 * 1048576, divisible by 4
    int n4 = n / 4;

    void* args[] = {(void*)&x, (void*)&cp, (void*)&knots, (void*)&ws, (void*)&out, (void*)&n4};
    hipLaunchCooperativeKernel((const void*)spline_fused, dim3(NB), dim3(NT), args, 0, stream);
}